// Round 1
// baseline (145.404 us; speedup 1.0000x reference)
//
#include <hip/hip_runtime.h>
#include <hip/hip_bf16.h>
#include <math.h>

#define T_LEN   7680
#define NSEG    59
#define NBINS   45
#define CH_PB   16      // channels per block
#define NBLK    256     // persistent blocks (1 per CU)

using bf16x8 = __attribute__((ext_vector_type(8))) short;
using f32x4  = __attribute__((ext_vector_type(4))) float;

__device__ __forceinline__ unsigned f2bf(float f) {
    unsigned u = __builtin_bit_cast(unsigned, f);
    return (u + 0x7FFFu + ((u >> 16) & 1u)) >> 16;   // RNE fp32->bf16
}

// Basis table in d_ws: mt[96][256] bf16. col j=2i -> cos(2pi(i+1)n/256),
// j=2i+1 -> -sin(...). cols 90..95 are zero padding.
__global__ void build_basis_kernel(unsigned short* __restrict__ mt) {
    int j = blockIdx.x, n = threadIdx.x;
    float v = 0.f;
    if (j < 90) {
        int k = (j >> 1) + 1;
        int m = (k * n) & 255;                      // exact periodic reduction
        float th = (float)m * 0.02454369260617026f; // 2*pi/256
        v = (j & 1) ? (-sinf(th)) : cosf(th);
    }
    mt[j * 256 + n] = (unsigned short)f2bf(v);
}

__global__ __launch_bounds__(256, 1)
void welch_main_kernel(const float* __restrict__ x,
                       const unsigned short* __restrict__ mt,
                       float* __restrict__ out) {
    __shared__ __align__(16) float          xraw[T_LEN];   // 30720 B
    __shared__ __align__(16) unsigned short Sm[64 * 256];  // 32768 B bf16, swizzled rows
    __shared__ __align__(16) float          win[256];
    __shared__ float hsum[60];
    __shared__ float psum[96];

    const int tid  = threadIdx.x;
    const int lane = tid & 63;
    const int w    = tid >> 6;

    // periodic hann
    win[tid] = 0.5f - 0.5f * cosf((float)tid * 0.02454369260617026f);

    // Preload ALL B fragments into registers: 6 col-tiles x 8 k-steps.
    // B frag for 16x16x32: lane holds B[k = 32*k0 + (lane>>4)*8 + i][col = ct*16 + (lane&15)]
    // = mt row (col), 8 contiguous bf16. 192 VGPRs, lives across the whole channel loop.
    bf16x8 breg[6][8];
    {
        const int col0 = lane & 15;
        const int kq   = (lane >> 4) * 8;
        #pragma unroll
        for (int ct = 0; ct < 6; ++ct)
            #pragma unroll
            for (int k0 = 0; k0 < 8; ++k0)
                breg[ct][k0] = *reinterpret_cast<const bf16x8*>(
                    mt + (ct * 16 + col0) * 256 + k0 * 32 + kq);
    }

    const int ch0 = blockIdx.x * CH_PB;

    // Async stage one channel (7680 fp32 = 1920 x 16B chunks = 30 full waves)
    auto issue_x = [&](int ch) {
        const float* gx = x + (size_t)ch * T_LEN;
        #pragma unroll
        for (int i = 0; i < 8; ++i) {
            int idx = i * 256 + tid;          // 16B chunk id
            if (idx < 1920) {
                char* lp = (char*)xraw + (size_t)(i * 256 + (tid & ~63)) * 16; // wave-uniform base
                __builtin_amdgcn_global_load_lds(
                    (const __attribute__((address_space(1))) void*)(gx + idx * 4),
                    (__attribute__((address_space(3))) void*)lp, 16, 0, 0);
            }
        }
    };

    issue_x(ch0);
    __syncthreads();   // compiler drains vmcnt here -> xraw ready; win visible

    for (int it = 0; it < CH_PB; ++it) {
        const int ch = ch0 + it;

        // ---- phase M: half-segment sums (mean[s] = (h[s]+h[s+1])/256), clear psum
        for (int hh = w; hh < 60; hh += 4) {
            float v = xraw[hh * 128 + lane] + xraw[hh * 128 + 64 + lane];
            v += __shfl_xor(v, 1);  v += __shfl_xor(v, 2);  v += __shfl_xor(v, 4);
            v += __shfl_xor(v, 8);  v += __shfl_xor(v, 16); v += __shfl_xor(v, 32);
            if (lane == 0) hsum[hh] = v;
        }
        if (tid < 96) psum[tid] = 0.f;
        __syncthreads();

        // ---- phase S: build detrended+windowed segments, bf16, XOR-swizzled rows.
        // Wave handles whole rows: lane covers n = 4*lane..4*lane+3 (one b128 read,
        // one b64 write). Rows 59..63 zero-padded.
        for (int s = w; s < 64; s += 4) {
            unsigned addr = ((unsigned)s * 512u + 8u * (unsigned)lane)
                            ^ (unsigned)((s & 7) << 4);
            uint2 pk;
            if (s < NSEG) {
                float mean = (hsum[s] + hsum[s + 1]) * (1.f / 256.f);
                f32x4 xv = *reinterpret_cast<const f32x4*>(&xraw[s * 128 + 4 * lane]);
                f32x4 wv = *reinterpret_cast<const f32x4*>(&win[4 * lane]);
                unsigned b0 = f2bf((xv[0] - mean) * wv[0]);
                unsigned b1 = f2bf((xv[1] - mean) * wv[1]);
                unsigned b2 = f2bf((xv[2] - mean) * wv[2]);
                unsigned b3 = f2bf((xv[3] - mean) * wv[3]);
                pk.x = b0 | (b1 << 16);
                pk.y = b2 | (b3 << 16);
            } else {
                pk.x = 0u; pk.y = 0u;
            }
            *reinterpret_cast<uint2*>((char*)Sm + addr) = pk;
        }
        __syncthreads();

        // prefetch next channel's x under the MFMA phase (xraw free now)
        if (it + 1 < CH_PB) issue_x(ch + 1);

        // ---- phase G: wave w owns rows 16w..16w+15; 8 k-steps x 6 col-tiles.
        f32x4 acc[6];
        #pragma unroll
        for (int ct = 0; ct < 6; ++ct) acc[ct] = (f32x4){0.f, 0.f, 0.f, 0.f};
        {
            const int arow       = w * 16 + (lane & 15);
            const unsigned abase = (unsigned)arow * 512u;
            const unsigned aswz  = (unsigned)((arow & 7) << 4);
            const unsigned kq16  = (unsigned)((lane >> 4) * 16);
            #pragma unroll
            for (int k0 = 0; k0 < 8; ++k0) {
                bf16x8 a = *reinterpret_cast<const bf16x8*>(
                    (char*)Sm + ((abase + (unsigned)k0 * 64u + kq16) ^ aswz));
                #pragma unroll
                for (int ct = 0; ct < 6; ++ct)
                    acc[ct] = __builtin_amdgcn_mfma_f32_16x16x32_bf16(
                        a, breg[ct][k0], acc[ct], 0, 0, 0);
            }
        }

        // ---- phase E: sum of squares over segment rows -> psum[96].
        // C/D layout: col = lane&15, row_in_tile = (lane>>4)*4 + reg.
        #pragma unroll
        for (int ct = 0; ct < 6; ++ct) {
            float p = acc[ct][0]*acc[ct][0] + acc[ct][1]*acc[ct][1]
                    + acc[ct][2]*acc[ct][2] + acc[ct][3]*acc[ct][3];
            p += __shfl_xor(p, 16);
            p += __shfl_xor(p, 32);
            if (lane < 16) atomicAdd(&psum[ct * 16 + lane], p);
        }
        __syncthreads();   // psum complete; vmcnt drained -> next xraw ready

        // ---- phase O: psd = (Re^2+Im^2)*2/(fs*sum(w^2)*nseg); log1p
        if (tid < NBINS) {
            const float CNORM = 2.0f / (24576.0f * 59.0f); // fs*sum(w^2)=256*96
            float psd = (psum[2 * tid] + psum[2 * tid + 1]) * CNORM;
            out[(size_t)ch * NBINS + tid] = log1pf(psd);
        }
        __syncthreads();   // protect psum/hsum reuse next iteration
    }
}

extern "C" void kernel_launch(void* const* d_in, const int* in_sizes, int n_in,
                              void* d_out, int out_size, void* d_ws, size_t ws_size,
                              hipStream_t stream) {
    const float* x = (const float*)d_in[0];
    float* out = (float*)d_out;
    unsigned short* mt = (unsigned short*)d_ws;   // 96*256*2 = 49152 B

    build_basis_kernel<<<96, 256, 0, stream>>>(mt);
    welch_main_kernel<<<NBLK, 256, 0, stream>>>(x, mt, out);
}

// Round 2
// 60.583 us; speedup vs baseline: 2.4001x; 2.4001x over previous
//
#include <hip/hip_runtime.h>
#include <hip/hip_bf16.h>
#include <math.h>

#define T_LEN   7680
#define NSEG    59
#define NBINS   45

using bf16x8 = __attribute__((ext_vector_type(8))) short;
using f32x4  = __attribute__((ext_vector_type(4))) float;

__device__ __forceinline__ unsigned f2bf(float f) {
    unsigned u = __builtin_bit_cast(unsigned, f);
    return (u + 0x7FFFu + ((u >> 16) & 1u)) >> 16;   // RNE fp32->bf16
}

// Basis table mt[96][256] bf16, GEMM runs on RAW x (detrend+window folded in):
//   col j=2i   : w_n*cos(2pi(i+1)n/256)      (i=0..44)
//   col j=2i+1 : -w_n*sin(2pi(i+1)n/256)
//   col 0 ALSO adds +0.25: exact detrend correction for k=1 real part, since
//   FFT_k(w*(x-mu)) = A_k - mu*W_k, W_1=-64, mu=S/256 -> Y1re = A1re + S/4.
//   All other bins unaffected by detrend (W_k=0 for |k|>=2; Im W_1 = 0).
__global__ void build_basis_kernel(unsigned short* __restrict__ mt) {
    int j = blockIdx.x, n = threadIdx.x;
    const float TH = 0.02454369260617026f;           // 2*pi/256
    float w = 0.5f - 0.5f * cosf((float)n * TH);     // periodic hann
    float v = 0.f;
    if (j < 90) {
        int k = (j >> 1) + 1;
        int m = (k * n) & 255;                       // exact periodic reduction
        float th = (float)m * TH;
        v = (j & 1) ? (-w * sinf(th)) : (w * cosf(th));
        if (j == 0) v += 0.25f;                      // fold detrend into k=1 re
    }
    mt[j * 256 + n] = (unsigned short)f2bf(v);
}

__global__ __launch_bounds__(256, 3)
void welch_main_kernel(const float* __restrict__ x,
                       const unsigned short* __restrict__ mt,
                       float* __restrict__ out) {
    __shared__ __align__(16) unsigned short Sm[64 * 256];  // 32 KB, swizzled rows
    __shared__ float psum[96];

    const int tid  = threadIdx.x;
    const int lane = tid & 63;
    const int w    = tid >> 6;
    const int ch   = blockIdx.x;
    const float* gx = x + (size_t)ch * T_LEN;

    // ---- B fragments: wave w owns MFMA pairs p=6w..6w+5, p = ct*4 + rt.
    // cts touched: ctA=(6w)>>2, ctB=(6w+5)>>2  (<=2 tiles -> 64 VGPR breg).
    const int ctA = (6 * w) >> 2;
    const int ctB = (6 * w + 5) >> 2;
    const int col0 = lane & 15;
    const int kq   = (lane >> 4) * 8;
    bf16x8 bregA[8], bregB[8];
    #pragma unroll
    for (int k0 = 0; k0 < 8; ++k0) {
        bregA[k0] = *reinterpret_cast<const bf16x8*>(
            mt + (ctA * 16 + col0) * 256 + k0 * 32 + kq);
        bregB[k0] = *reinterpret_cast<const bf16x8*>(
            mt + (ctB * 16 + col0) * 256 + k0 * 32 + kq);
    }

    if (tid < 96) psum[tid] = 0.f;

    // ---- phase S: raw x -> bf16 segments in LDS (XOR-swizzled rows).
    // chunk c covers x[4c..4c+3]; half hh=c>>5 is first half of seg hh and
    // second half of seg hh-1 -> one global read serves both LDS writes.
    #pragma unroll
    for (int i = 0; i < 8; ++i) {
        int c = i * 256 + tid;
        if (c < 1920) {
            f32x4 xv = *reinterpret_cast<const f32x4*>(gx + 4 * c);
            unsigned b0 = f2bf(xv[0]), b1 = f2bf(xv[1]);
            unsigned b2 = f2bf(xv[2]), b3 = f2bf(xv[3]);
            uint2 pk; pk.x = b0 | (b1 << 16); pk.y = b2 | (b3 << 16);
            int hh = c >> 5, q = c & 31;
            if (hh < NSEG) {
                unsigned a = (unsigned)(hh * 512 + 8 * q) ^ (unsigned)((hh & 7) << 4);
                *reinterpret_cast<uint2*>((char*)Sm + a) = pk;
            }
            if (hh > 0) {
                int s = hh - 1;
                unsigned a = (unsigned)(s * 512 + 256 + 8 * q) ^ (unsigned)((s & 7) << 4);
                *reinterpret_cast<uint2*>((char*)Sm + a) = pk;
            }
        }
    }
    // zero-pad rows 59..63 (read by rowtile 3)
    for (int z = tid; z < 320; z += 256) {
        int row = 59 + (z >> 6), q = z & 63;
        unsigned a = (unsigned)(row * 512 + 8 * q) ^ (unsigned)((row & 7) << 4);
        *reinterpret_cast<uint2*>((char*)Sm + a) = make_uint2(0u, 0u);
    }
    __syncthreads();

    // ---- phase G: 6 (ct,rt) pairs per wave, A-frag read once per rowtile.
    f32x4 accA[4], accB[4];
    #pragma unroll
    for (int r = 0; r < 4; ++r) {
        accA[r] = (f32x4){0.f, 0.f, 0.f, 0.f};
        accB[r] = (f32x4){0.f, 0.f, 0.f, 0.f};
    }
    const unsigned kq16 = (unsigned)((lane >> 4) * 16);
    #pragma unroll
    for (int rt = 0; rt < 4; ++rt) {
        const int arow = rt * 16 + (lane & 15);
        const unsigned abase = (unsigned)arow * 512u;
        const unsigned aswz  = (unsigned)((arow & 7) << 4);
        bf16x8 a[8];
        #pragma unroll
        for (int k0 = 0; k0 < 8; ++k0)
            a[k0] = *reinterpret_cast<const bf16x8*>(
                (char*)Sm + ((abase + (unsigned)k0 * 64u + kq16) ^ aswz));
        const bool oA = (unsigned)(ctA * 4 + rt - 6 * w) < 6u;
        const bool oB = (unsigned)(ctB * 4 + rt - 6 * w) < 6u;
        if (oA) {
            #pragma unroll
            for (int k0 = 0; k0 < 8; ++k0)
                accA[rt] = __builtin_amdgcn_mfma_f32_16x16x32_bf16(
                    a[k0], bregA[k0], accA[rt], 0, 0, 0);
        }
        if (oB && ctB != ctA) {
            #pragma unroll
            for (int k0 = 0; k0 < 8; ++k0)
                accB[rt] = __builtin_amdgcn_mfma_f32_16x16x32_bf16(
                    a[k0], bregB[k0], accB[rt], 0, 0, 0);
        }
    }

    // ---- phase E: colsum = sum over segments of acc^2, per owned ct.
    // C/D layout: col = lane&15, row = rt*16 + (lane>>4)*4 + reg.
    {
        float pA = 0.f, pB = 0.f;
        #pragma unroll
        for (int rt = 0; rt < 4; ++rt) {
            if ((unsigned)(ctA * 4 + rt - 6 * w) < 6u)
                pA += accA[rt][0]*accA[rt][0] + accA[rt][1]*accA[rt][1]
                    + accA[rt][2]*accA[rt][2] + accA[rt][3]*accA[rt][3];
            if ((unsigned)(ctB * 4 + rt - 6 * w) < 6u && ctB != ctA)
                pB += accB[rt][0]*accB[rt][0] + accB[rt][1]*accB[rt][1]
                    + accB[rt][2]*accB[rt][2] + accB[rt][3]*accB[rt][3];
        }
        pA += __shfl_xor(pA, 16);  pA += __shfl_xor(pA, 32);
        pB += __shfl_xor(pB, 16);  pB += __shfl_xor(pB, 32);
        if (lane < 16) {
            atomicAdd(&psum[ctA * 16 + col0], pA);
            if (ctB != ctA) atomicAdd(&psum[ctB * 16 + col0], pB);
        }
    }
    __syncthreads();

    // ---- output: psd_k = (re^2+im^2 summed)*2/(fs*sum(w^2)*nseg); log1p
    if (tid < NBINS) {
        const float CNORM = 2.0f / (24576.0f * 59.0f);  // fs*sum(w^2) = 256*96
        float psd = (psum[2 * tid] + psum[2 * tid + 1]) * CNORM;
        out[(size_t)ch * NBINS + tid] = log1pf(psd);
    }
}

extern "C" void kernel_launch(void* const* d_in, const int* in_sizes, int n_in,
                              void* d_out, int out_size, void* d_ws, size_t ws_size,
                              hipStream_t stream) {
    const float* x = (const float*)d_in[0];
    float* out = (float*)d_out;
    unsigned short* mt = (unsigned short*)d_ws;   // 96*256*2 = 49152 B

    build_basis_kernel<<<96, 256, 0, stream>>>(mt);
    welch_main_kernel<<<4096, 256, 0, stream>>>(x, mt, out);
}

// Round 6
// 59.771 us; speedup vs baseline: 2.4327x; 1.0136x over previous
//
#include <hip/hip_runtime.h>
#include <hip/hip_bf16.h>
#include <math.h>

#define T_LEN   7680
#define NSEG    59
#define NBINS   45

using bf16x8 = __attribute__((ext_vector_type(8))) short;
using f32x4  = __attribute__((ext_vector_type(4))) float;

__device__ __forceinline__ unsigned f2bf(float f) {
    unsigned u = __builtin_bit_cast(unsigned, f);
    return (u + 0x7FFFu + ((u >> 16) & 1u)) >> 16;   // RNE fp32->bf16
}

// Basis table mt[96][256] bf16, GEMM runs on RAW x (detrend+window folded in):
//   col j=2i   : w_n*cos(2pi(i+1)n/256)      (i=0..44)
//   col j=2i+1 : -w_n*sin(2pi(i+1)n/256)
//   col 0 ALSO adds +0.25: exact detrend correction for k=1 real part, since
//   FFT_k(w*(x-mu)) = A_k - mu*W_k, W_1=-64, mu=S/256 -> Y1re = A1re + S/4.
//   All other bins unaffected by detrend (W_k=0 for |k|>=2; Im W_1 = 0).
__global__ void build_basis_kernel(unsigned short* __restrict__ mt) {
    int j = blockIdx.x, n = threadIdx.x;
    const float TH = 0.02454369260617026f;           // 2*pi/256
    float w = 0.5f - 0.5f * cosf((float)n * TH);     // periodic hann
    float v = 0.f;
    if (j < 90) {
        int k = (j >> 1) + 1;
        int m = (k * n) & 255;                       // exact periodic reduction
        float th = (float)m * TH;
        v = (j & 1) ? (-w * sinf(th)) : (w * cosf(th));
        if (j == 0) v += 0.25f;                      // fold detrend into k=1 re
    }
    mt[j * 256 + n] = (unsigned short)f2bf(v);
}

// R2-VERBATIM kernel body (the proven-correct structure: breg loads early,
// a[8] fragment array, ownership guards OUTSIDE the k0 loop, separate
// square-sum phase). Single variable changed vs R2: launch_bounds 3 -> 4.
// Bisect history: fused-G+E (guards inside k0 loop) convicted by elimination
// across R3/R4/R5 (identical absmax 4.211e-3 under two layouts and two lb
// values). NEVER re-fuse the MFMA guards into the K loop.
__global__ __launch_bounds__(256, 4)
void welch_main_kernel(const float* __restrict__ x,
                       const unsigned short* __restrict__ mt,
                       float* __restrict__ out) {
    __shared__ __align__(16) unsigned short Sm[64 * 256];  // 32 KB, swizzled rows
    __shared__ float psum[96];

    const int tid  = threadIdx.x;
    const int lane = tid & 63;
    const int w    = tid >> 6;
    const int ch   = blockIdx.x;
    const float* gx = x + (size_t)ch * T_LEN;

    // ---- B fragments: wave w owns MFMA pairs p=6w..6w+5, p = ct*4 + rt.
    // cts touched: ctA=(6w)>>2, ctB=(6w+5)>>2  (<=2 tiles -> 64 VGPR breg).
    const int ctA = (6 * w) >> 2;
    const int ctB = (6 * w + 5) >> 2;
    const int col0 = lane & 15;
    const int kq   = (lane >> 4) * 8;
    bf16x8 bregA[8], bregB[8];
    #pragma unroll
    for (int k0 = 0; k0 < 8; ++k0) {
        bregA[k0] = *reinterpret_cast<const bf16x8*>(
            mt + (ctA * 16 + col0) * 256 + k0 * 32 + kq);
        bregB[k0] = *reinterpret_cast<const bf16x8*>(
            mt + (ctB * 16 + col0) * 256 + k0 * 32 + kq);
    }

    if (tid < 96) psum[tid] = 0.f;

    // ---- phase S: raw x -> bf16 segments in LDS (XOR-swizzled rows).
    // chunk c covers x[4c..4c+3]; half hh=c>>5 is first half of seg hh and
    // second half of seg hh-1 -> one global read serves both LDS writes.
    #pragma unroll
    for (int i = 0; i < 8; ++i) {
        int c = i * 256 + tid;
        if (c < 1920) {
            f32x4 xv = *reinterpret_cast<const f32x4*>(gx + 4 * c);
            unsigned b0 = f2bf(xv[0]), b1 = f2bf(xv[1]);
            unsigned b2 = f2bf(xv[2]), b3 = f2bf(xv[3]);
            uint2 pk; pk.x = b0 | (b1 << 16); pk.y = b2 | (b3 << 16);
            int hh = c >> 5, q = c & 31;
            if (hh < NSEG) {
                unsigned a = (unsigned)(hh * 512 + 8 * q) ^ (unsigned)((hh & 7) << 4);
                *reinterpret_cast<uint2*>((char*)Sm + a) = pk;
            }
            if (hh > 0) {
                int s = hh - 1;
                unsigned a = (unsigned)(s * 512 + 256 + 8 * q) ^ (unsigned)((s & 7) << 4);
                *reinterpret_cast<uint2*>((char*)Sm + a) = pk;
            }
        }
    }
    // zero-pad rows 59..63 (read by rowtile 3)
    for (int z = tid; z < 320; z += 256) {
        int row = 59 + (z >> 6), q = z & 63;
        unsigned a = (unsigned)(row * 512 + 8 * q) ^ (unsigned)((row & 7) << 4);
        *reinterpret_cast<uint2*>((char*)Sm + a) = make_uint2(0u, 0u);
    }
    __syncthreads();

    // ---- phase G: 6 (ct,rt) pairs per wave, A-frag read once per rowtile.
    f32x4 accA[4], accB[4];
    #pragma unroll
    for (int r = 0; r < 4; ++r) {
        accA[r] = (f32x4){0.f, 0.f, 0.f, 0.f};
        accB[r] = (f32x4){0.f, 0.f, 0.f, 0.f};
    }
    const unsigned kq16 = (unsigned)((lane >> 4) * 16);
    #pragma unroll
    for (int rt = 0; rt < 4; ++rt) {
        const int arow = rt * 16 + (lane & 15);
        const unsigned abase = (unsigned)arow * 512u;
        const unsigned aswz  = (unsigned)((arow & 7) << 4);
        bf16x8 a[8];
        #pragma unroll
        for (int k0 = 0; k0 < 8; ++k0)
            a[k0] = *reinterpret_cast<const bf16x8*>(
                (char*)Sm + ((abase + (unsigned)k0 * 64u + kq16) ^ aswz));
        const bool oA = (unsigned)(ctA * 4 + rt - 6 * w) < 6u;
        const bool oB = (unsigned)(ctB * 4 + rt - 6 * w) < 6u;
        if (oA) {
            #pragma unroll
            for (int k0 = 0; k0 < 8; ++k0)
                accA[rt] = __builtin_amdgcn_mfma_f32_16x16x32_bf16(
                    a[k0], bregA[k0], accA[rt], 0, 0, 0);
        }
        if (oB && ctB != ctA) {
            #pragma unroll
            for (int k0 = 0; k0 < 8; ++k0)
                accB[rt] = __builtin_amdgcn_mfma_f32_16x16x32_bf16(
                    a[k0], bregB[k0], accB[rt], 0, 0, 0);
        }
    }

    // ---- phase E: colsum = sum over segments of acc^2, per owned ct.
    // C/D layout: col = lane&15, row = rt*16 + (lane>>4)*4 + reg.
    {
        float pA = 0.f, pB = 0.f;
        #pragma unroll
        for (int rt = 0; rt < 4; ++rt) {
            if ((unsigned)(ctA * 4 + rt - 6 * w) < 6u)
                pA += accA[rt][0]*accA[rt][0] + accA[rt][1]*accA[rt][1]
                    + accA[rt][2]*accA[rt][2] + accA[rt][3]*accA[rt][3];
            if ((unsigned)(ctB * 4 + rt - 6 * w) < 6u && ctB != ctA)
                pB += accB[rt][0]*accB[rt][0] + accB[rt][1]*accB[rt][1]
                    + accB[rt][2]*accB[rt][2] + accB[rt][3]*accB[rt][3];
        }
        pA += __shfl_xor(pA, 16);  pA += __shfl_xor(pA, 32);
        pB += __shfl_xor(pB, 16);  pB += __shfl_xor(pB, 32);
        if (lane < 16) {
            atomicAdd(&psum[ctA * 16 + col0], pA);
            if (ctB != ctA) atomicAdd(&psum[ctB * 16 + col0], pB);
        }
    }
    __syncthreads();

    // ---- output: psd_k = (re^2+im^2 summed)*2/(fs*sum(w^2)*nseg); log1p
    if (tid < NBINS) {
        const float CNORM = 2.0f / (24576.0f * 59.0f);  // fs*sum(w^2) = 256*96
        float psd = (psum[2 * tid] + psum[2 * tid + 1]) * CNORM;
        out[(size_t)ch * NBINS + tid] = log1pf(psd);
    }
}

extern "C" void kernel_launch(void* const* d_in, const int* in_sizes, int n_in,
                              void* d_out, int out_size, void* d_ws, size_t ws_size,
                              hipStream_t stream) {
    const float* x = (const float*)d_in[0];
    float* out = (float*)d_out;
    unsigned short* mt = (unsigned short*)d_ws;   // 96*256*2 = 49152 B

    build_basis_kernel<<<96, 256, 0, stream>>>(mt);
    welch_main_kernel<<<4096, 256, 0, stream>>>(x, mt, out);
}